// Round 3
// baseline (855.094 us; speedup 1.0000x reference)
//
#include <hip/hip_runtime.h>
#include <hip/hip_bf16.h>
#include <math.h>

#define TB 4
#define TT 4096
#define HH 2048
#define DD 256
#define NN 32768
#define HQ 512
#define MM (TB*TT)

typedef __attribute__((ext_vector_type(8))) short bf16x8;
typedef __attribute__((ext_vector_type(4))) float f32x4;

__device__ inline unsigned short f2bf(float x){
  __hip_bfloat16 h = __float2bfloat16(x);
  return *reinterpret_cast<unsigned short*>(&h);
}

__device__ inline void split_bf16(float a, unsigned short &hi, unsigned short &lo){
  __hip_bfloat16 h = __float2bfloat16(a);
  hi = *reinterpret_cast<unsigned short*>(&h);
  float hf = __bfloat162float(h);
  __hip_bfloat16 l = __float2bfloat16(a - hf);
  lo = *reinterpret_cast<unsigned short*>(&l);
}

__device__ inline bf16x8 as_bf16x8(uint4 u){ bf16x8 r; __builtin_memcpy(&r,&u,16); return r; }

// K1: batch-mean only (bf16 out)
__global__ __launch_bounds__(256) void k_mean(const float* __restrict__ h,
    unsigned short* __restrict__ hmb){
  const size_t i = (size_t)blockIdx.x*256 + threadIdx.x;   // float4 idx in [T*H/4]
  const size_t TH4 = (size_t)TT*HH/4;
  const float4* p = (const float4*)h;
  float4 v0 = p[i], v1 = p[i+TH4], v2 = p[i+2*TH4], v3 = p[i+3*TH4];
  float4 m;
  m.x = 0.25f*(v0.x+v1.x+v2.x+v3.x);
  m.y = 0.25f*(v0.y+v1.y+v2.y+v3.y);
  m.z = 0.25f*(v0.z+v1.z+v2.z+v3.z);
  m.w = 0.25f*(v0.w+v1.w+v2.w+v3.w);
  ushort4 o; o.x = f2bf(m.x); o.y = f2bf(m.y); o.z = f2bf(m.z); o.w = f2bf(m.w);
  *(ushort4*)(hmb + i*4) = o;
}

// K2: W_g1||W_p1 -> bf16 hi/lo [1024,2048]
__global__ __launch_bounds__(256) void k_cvt_w(const float* __restrict__ Wg1,
    const float* __restrict__ Wp1,
    unsigned short* __restrict__ Whi, unsigned short* __restrict__ Wlo){
  const int idx4 = blockIdx.x*256 + threadIdx.x;     // 524288 float4s
  const int n = idx4 >> 9;                           // row 0..1023
  const int c = (idx4 & 511)*4;
  const float* src = (n < HQ) ? (Wg1 + (size_t)n*HH + c) : (Wp1 + (size_t)(n-HQ)*HH + c);
  float4 v = *(const float4*)src;
  ushort4 hi4, lo4;
  split_bf16(v.x, hi4.x, lo4.x);
  split_bf16(v.y, hi4.y, lo4.y);
  split_bf16(v.z, hi4.z, lo4.z);
  split_bf16(v.w, hi4.w, lo4.w);
  *(ushort4*)(Whi + (size_t)idx4*4) = hi4;
  *(ushort4*)(Wlo + (size_t)idx4*4) = lo4;
}

// K2b: W_obs -> bf16 [256,2048]
__global__ __launch_bounds__(256) void k_cvt_wobs(const float* __restrict__ W,
    unsigned short* __restrict__ Wb){
  const int idx4 = blockIdx.x*256 + threadIdx.x;     // 131072 float4s
  float4 v = *(const float4*)(W + (size_t)idx4*4);
  ushort4 o; o.x = f2bf(v.x); o.y = f2bf(v.y); o.z = f2bf(v.z); o.w = f2bf(v.w);
  *(ushort4*)(Wb + (size_t)idx4*4) = o;
}

// K3: obs_mean = hmb @ wob^T  (bf16 MFMA, f32 out)  [4096,2048]x[256,2048]^T
__global__ __launch_bounds__(256) void k_obs(const unsigned short* __restrict__ A,
    const unsigned short* __restrict__ Bw, float* __restrict__ C){
  const int n0 = blockIdx.x*128, m0 = blockIdx.y*128;
  const int tid = threadIdx.x;
  const int w = tid>>6, lane = tid&63, lr = lane&15, q = lane>>4;
  __shared__ __align__(16) unsigned short Bs[128][40];
  f32x4 acc[2][8] = {};
  for (int k0 = 0; k0 < HH; k0 += 32){
    __syncthreads();
    #pragma unroll
    for (int ii = 0; ii < 2; ii++){
      int idx = tid + ii*256;
      int row = idx >> 2, c8 = (idx & 3)*8;
      *(uint4*)&Bs[row][c8] = *(const uint4*)(Bw + (size_t)(n0+row)*HH + k0 + c8);
    }
    bf16x8 a[2];
    #pragma unroll
    for (int i = 0; i < 2; i++)
      a[i] = as_bf16x8(*(const uint4*)(A + (size_t)(m0 + w*32 + i*16 + lr)*HH + k0 + q*8));
    __syncthreads();
    #pragma unroll
    for (int j = 0; j < 8; j++){
      bf16x8 b = as_bf16x8(*(const uint4*)&Bs[j*16 + lr][q*8]);
      #pragma unroll
      for (int i = 0; i < 2; i++)
        acc[i][j] = __builtin_amdgcn_mfma_f32_16x16x32_bf16(a[i], b, acc[i][j], 0, 0, 0);
    }
  }
  #pragma unroll
  for (int i = 0; i < 2; i++)
    #pragma unroll
    for (int j = 0; j < 8; j++)
      #pragma unroll
      for (int r = 0; r < 4; r++)
        C[(size_t)(m0 + w*32 + i*16 + q*4 + r)*DD + n0 + j*16 + lr] = acc[i][j][r];
}

// K4: gate/prec layer1, split-bf16 3-product MFMA, fp32 A loaded direct +
// in-kernel split, reg-prefetch pipeline, n_block=256, fused relu*w2 epilogue.
__global__ __launch_bounds__(256, 2) void k_gp(const float* __restrict__ A,
    const unsigned short* __restrict__ Whi, const unsigned short* __restrict__ Wlo,
    const float* __restrict__ bg1, const float* __restrict__ bp1,
    const float* __restrict__ Wg2, const float* __restrict__ Wp2,
    float* __restrict__ z1, float* __restrict__ z2){
  const int n0 = blockIdx.x*256;     // 0,256,512,768 in concat [gate|prec]
  const int m0 = blockIdx.y*128;
  const int tid = threadIdx.x;
  const int w = tid>>6, lane = tid&63, lr = lane&15, q = lane>>4;
  __shared__ __align__(16) unsigned short Bhi[256][40];
  __shared__ __align__(16) unsigned short Blo[256][40];
  f32x4 acc[2][16] = {};

  const unsigned short* whp = Whi + (size_t)n0*HH;
  const unsigned short* wlp = Wlo + (size_t)n0*HH;
  const float* arp[2];
  arp[0] = A + (size_t)(m0 + w*32 + lr)*HH + q*8;
  arp[1] = A + (size_t)(m0 + w*32 + 16 + lr)*HH + q*8;

  uint4 wh[4], wl[4];
  float4 a0[2], a1[2];
  // preload chunk 0 (W into regs, A into regs)
  #pragma unroll
  for (int ii = 0; ii < 4; ii++){
    int idx = tid + ii*256;
    int row = idx >> 2, c8 = (idx & 3)*8;
    wh[ii] = *(const uint4*)(whp + (size_t)row*HH + c8);
    wl[ii] = *(const uint4*)(wlp + (size_t)row*HH + c8);
  }
  #pragma unroll
  for (int i = 0; i < 2; i++){ a0[i] = *(const float4*)(arp[i]); a1[i] = *(const float4*)(arp[i]+4); }
  #pragma unroll
  for (int ii = 0; ii < 4; ii++){
    int idx = tid + ii*256;
    int row = idx >> 2, c8 = (idx & 3)*8;
    *(uint4*)&Bhi[row][c8] = wh[ii];
    *(uint4*)&Blo[row][c8] = wl[ii];
  }
  __syncthreads();

  for (int k0 = 0; k0 < HH; k0 += 32){
    const bool last = (k0 + 32 >= HH);
    // prefetch next W chunk into regs (latency hidden under MFMA below)
    if (!last){
      #pragma unroll
      for (int ii = 0; ii < 4; ii++){
        int idx = tid + ii*256;
        int row = idx >> 2, c8 = (idx & 3)*8;
        wh[ii] = *(const uint4*)(whp + (size_t)row*HH + (k0+32) + c8);
        wl[ii] = *(const uint4*)(wlp + (size_t)row*HH + (k0+32) + c8);
      }
    }
    // convert current A fp32 -> hi/lo bf16 frags
    bf16x8 ah[2], al[2];
    #pragma unroll
    for (int i = 0; i < 2; i++){
      float av[8] = {a0[i].x,a0[i].y,a0[i].z,a0[i].w,a1[i].x,a1[i].y,a1[i].z,a1[i].w};
      #pragma unroll
      for (int e = 0; e < 8; e++){
        unsigned short h, l; split_bf16(av[e], h, l);
        ah[i][e] = (short)h; al[i][e] = (short)l;
      }
    }
    // prefetch next A chunk into regs
    if (!last){
      #pragma unroll
      for (int i = 0; i < 2; i++){
        a0[i] = *(const float4*)(arp[i] + k0 + 32);
        a1[i] = *(const float4*)(arp[i] + k0 + 36);
      }
    }
    // MFMA block: 16 n-tiles x 2 m-tiles x 3 products
    #pragma unroll
    for (int j = 0; j < 16; j++){
      bf16x8 bh = as_bf16x8(*(const uint4*)&Bhi[j*16 + lr][q*8]);
      bf16x8 bl = as_bf16x8(*(const uint4*)&Blo[j*16 + lr][q*8]);
      #pragma unroll
      for (int i = 0; i < 2; i++){
        acc[i][j] = __builtin_amdgcn_mfma_f32_16x16x32_bf16(ah[i], bh, acc[i][j], 0, 0, 0);
        acc[i][j] = __builtin_amdgcn_mfma_f32_16x16x32_bf16(al[i], bh, acc[i][j], 0, 0, 0);
        acc[i][j] = __builtin_amdgcn_mfma_f32_16x16x32_bf16(ah[i], bl, acc[i][j], 0, 0, 0);
      }
    }
    if (!last){
      __syncthreads();            // all waves done reading cur LDS
      #pragma unroll
      for (int ii = 0; ii < 4; ii++){
        int idx = tid + ii*256;
        int row = idx >> 2, c8 = (idx & 3)*8;
        *(uint4*)&Bhi[row][c8] = wh[ii];
        *(uint4*)&Blo[row][c8] = wl[ii];
      }
      __syncthreads();
    }
  }
  // epilogue: z[m] += sum_n relu(C[m,n] + b1[n]) * w2[n]
  const bool isP = (n0 >= HQ);
  const float* b1 = isP ? bp1 : bg1;
  const float* w2 = isP ? Wp2 : Wg2;
  float* zt = isP ? z2 : z1;
  const int nb = n0 - (isP ? HQ : 0);
  float bv[16], wv[16];
  #pragma unroll
  for (int j = 0; j < 16; j++){
    int n = nb + j*16 + lr;
    bv[j] = b1[n]; wv[j] = w2[n];
  }
  #pragma unroll
  for (int i = 0; i < 2; i++){
    float s[4];
    #pragma unroll
    for (int r = 0; r < 4; r++){
      float t = 0.f;
      #pragma unroll
      for (int j = 0; j < 16; j++)
        t += fmaxf(acc[i][j][r] + bv[j], 0.f) * wv[j];
      s[r] = t;
    }
    #pragma unroll
    for (int mk = 1; mk < 16; mk <<= 1)
      #pragma unroll
      for (int r = 0; r < 4; r++)
        s[r] += __shfl_xor(s[r], mk);
    if (lr == 0){
      #pragma unroll
      for (int r = 0; r < 4; r++)
        atomicAdd(&zt[m0 + w*32 + i*16 + q*4 + r], s[r]);
    }
  }
}

// K5: per-t finalize
__global__ __launch_bounds__(256) void k_obs_fin(const float* __restrict__ obs_mean,
    const float* __restrict__ z1, const float* __restrict__ z2,
    const float* __restrict__ bg2, const float* __restrict__ bp2,
    float* __restrict__ out0, float* __restrict__ out3,
    float* __restrict__ obs_radii, unsigned short* __restrict__ obf){
  const int t = blockIdx.x, tid = threadIdx.x;
  __shared__ float red[256];
  __shared__ float pmsh;
  if (tid < TB){
    float a = z1[tid*TT + t] + bg2[0];
    float b = z2[tid*TT + t] + bp2[0];
    float gate = 1.f/(1.f + expf(-a));
    float sp = (b > 0.f) ? (b + log1pf(expf(-b))) : log1pf(expf(b));
    red[tid] = gate * sp;
  }
  __syncthreads();
  if (tid == 0) pmsh = 0.25f*(red[0]+red[1]+red[2]+red[3]);
  __syncthreads();
  const float x = obs_mean[(size_t)t*DD + tid];
  red[tid] = x*x;
  __syncthreads();
  #pragma unroll
  for (int s = 128; s > 0; s >>= 1){ if (tid < s) red[tid] += red[tid+s]; __syncthreads(); }
  const float nrm = sqrtf(red[0]);
  const float pm = pmsh;
  __syncthreads();
  const float ob = (x / fmaxf(nrm, 1e-8f)) * pm;
  out0[(size_t)t*DD + tid] = ob;
  red[tid] = ob*ob;
  __syncthreads();
  #pragma unroll
  for (int s = 128; s > 0; s >>= 1){ if (tid < s) red[tid] += red[tid+s]; __syncthreads(); }
  const float r2 = sqrtf(red[0]);
  if (tid == 0){
    obs_radii[t] = r2;
    out3[t] = (r2 > 0.05f) ? 1.f : 0.f;
  }
  const float oa = ob / fmaxf(r2, 1e-8f);
  obf[(size_t)t*DD + tid] = f2bf(oa);
}

// K6: normalize beliefs -> bf16 angles
__global__ __launch_bounds__(256) void k_beliefs(const float* __restrict__ bel,
    unsigned short* __restrict__ bbf){
  const int n = (blockIdx.x*256 + threadIdx.x) >> 6;
  const int lane = threadIdx.x & 63;
  const float4 v = *(const float4*)(bel + (size_t)n*DD + lane*4);
  float s = v.x*v.x + v.y*v.y + v.z*v.z + v.w*v.w;
  #pragma unroll
  for (int m = 1; m < 64; m <<= 1) s += __shfl_xor(s, m);
  const float inv = 1.f / fmaxf(sqrtf(s), 1e-8f);
  ushort4 o;
  o.x = f2bf(v.x*inv); o.y = f2bf(v.y*inv); o.z = f2bf(v.z*inv); o.w = f2bf(v.w*inv);
  *(ushort4*)(bbf + (size_t)n*DD + lane*4) = o;
}

// K6b: any_active flag
__global__ __launch_bounds__(256) void k_any(const unsigned char* __restrict__ mask,
    int* __restrict__ flag){
  __shared__ int s;
  if (threadIdx.x == 0) s = 0;
  __syncthreads();
  int any = 0;
  for (int i = threadIdx.x; i < NN; i += 256) any |= (mask[i] != 0);
  if (any) s = 1;
  __syncthreads();
  if (threadIdx.x == 0) flag[0] = s;
}

// K7: fused sims + masked max/argmax. 2 m-tiles/wave (t_block=128), 16 n-splits.
__global__ __launch_bounds__(256) void k_sims(const unsigned short* __restrict__ obf,
    const unsigned short* __restrict__ bbf, const unsigned char* __restrict__ mask,
    float* __restrict__ pmax, int* __restrict__ pidx){
  const int t0 = blockIdx.x * 128;
  const int ns = blockIdx.y;                 // 0..15
  const int nbase0 = ns * (NN/16);
  const int tid = threadIdx.x;
  const int w = tid >> 6, lane = tid & 63;
  const int lr = lane & 15, q = lane >> 4;
  __shared__ __align__(16) unsigned short bt[64*264];
  __shared__ unsigned char am[64];
  bf16x8 afr[2][8];
  #pragma unroll
  for (int i = 0; i < 2; i++){
    const unsigned short* ap = obf + (size_t)(t0 + w*32 + i*16 + lr)*DD + q*8;
    #pragma unroll
    for (int ks = 0; ks < 8; ks++)
      afr[i][ks] = as_bf16x8(*(const uint4*)(ap + ks*32));
  }
  float vmax[2][4] = {{-INFINITY,-INFINITY,-INFINITY,-INFINITY},
                      {-INFINITY,-INFINITY,-INFINITY,-INFINITY}};
  int   vidx[2][4] = {{-1,-1,-1,-1},{-1,-1,-1,-1}};
  for (int it = 0; it < (NN/16)/64; it++){
    const int nb = nbase0 + it*64;
    __syncthreads();
    {
      const unsigned short* src = bbf + (size_t)nb*DD;
      #pragma unroll
      for (int i = 0; i < 8; i++){
        int c = tid + i*256;
        int row = c >> 5, c16 = c & 31;
        uint4 u = *(const uint4*)(src + row*DD + c16*8);
        *(uint4*)(bt + row*264 + c16*8) = u;
      }
      if (tid < 64) am[tid] = mask[nb + tid];
    }
    __syncthreads();
    #pragma unroll
    for (int sub = 0; sub < 4; sub++){
      f32x4 acc[2] = {{0.f,0.f,0.f,0.f},{0.f,0.f,0.f,0.f}};
      const unsigned short* bp = bt + (sub*16 + lr)*264 + q*8;
      #pragma unroll
      for (int ks = 0; ks < 8; ks++){
        bf16x8 bfr = as_bf16x8(*(const uint4*)(bp + ks*32));
        #pragma unroll
        for (int i = 0; i < 2; i++)
          acc[i] = __builtin_amdgcn_mfma_f32_16x16x32_bf16(afr[i][ks], bfr, acc[i], 0, 0, 0);
      }
      if (am[sub*16 + lr]){
        const int n = nb + sub*16 + lr;
        #pragma unroll
        for (int i = 0; i < 2; i++)
          #pragma unroll
          for (int r = 0; r < 4; r++)
            if (acc[i][r] > vmax[i][r]){ vmax[i][r] = acc[i][r]; vidx[i][r] = n; }
      }
    }
  }
  #pragma unroll
  for (int mk = 1; mk < 16; mk <<= 1){
    #pragma unroll
    for (int i = 0; i < 2; i++)
      #pragma unroll
      for (int r = 0; r < 4; r++){
        float om = __shfl_xor(vmax[i][r], mk);
        int   oi = __shfl_xor(vidx[i][r], mk);
        if (om > vmax[i][r] || (om == vmax[i][r] && (unsigned)oi < (unsigned)vidx[i][r])){
          vmax[i][r] = om; vidx[i][r] = oi;
        }
      }
  }
  if (lr == 0){
    #pragma unroll
    for (int i = 0; i < 2; i++)
      #pragma unroll
      for (int r = 0; r < 4; r++){
        const int t = t0 + w*32 + i*16 + q*4 + r;
        pmax[ns*TT + t] = vmax[i][r];
        pidx[ns*TT + t] = vidx[i][r];
      }
  }
}

// K8: combine n-splits + match logic
__global__ __launch_bounds__(256) void k_combine(const float* __restrict__ pmax,
    const int* __restrict__ pidx, const float* __restrict__ obs_radii,
    const int* __restrict__ flag, float* __restrict__ out1, float* __restrict__ out2){
  const int t = blockIdx.x*256 + threadIdx.x;
  float best = -INFINITY; int bi = -1;
  #pragma unroll
  for (int s = 0; s < 16; s++){
    float m = pmax[s*TT + t];
    if (m > best){ best = m; bi = pidx[s*TT + t]; }
  }
  const bool anyA = (flag[0] != 0);
  const bool mf = obs_radii[t] > 0.05f;
  const bool matched = mf && anyA && (best > 0.5f);
  out1[t] = matched ? best : 0.f;
  out2[t] = matched ? (float)bi : -1.f;
}

extern "C" void kernel_launch(void* const* d_in, const int* in_sizes, int n_in,
                              void* d_out, int out_size, void* d_ws, size_t ws_size,
                              hipStream_t stream) {
  const float* hidden = (const float*)d_in[0];
  const float* beliefs = (const float*)d_in[1];
  const unsigned char* amask = (const unsigned char*)d_in[2];
  const float* W_obs = (const float*)d_in[3];
  const float* W_g1 = (const float*)d_in[4];
  const float* b_g1 = (const float*)d_in[5];
  const float* W_g2 = (const float*)d_in[6];
  const float* b_g2 = (const float*)d_in[7];
  const float* W_p1 = (const float*)d_in[8];
  const float* b_p1 = (const float*)d_in[9];
  const float* W_p2 = (const float*)d_in[10];
  const float* b_p2 = (const float*)d_in[11];

  char* ws = (char*)d_ws;
  const size_t HMB_OFF  = 0;                 // 4096*2048*2 = 16777216
  const size_t WHI_OFF  = 16777216;          // 1024*2048*2 = 4194304
  const size_t WLO_OFF  = 20971520;          // 4194304
  const size_t WOB_OFF  = 25165824;          // 256*2048*2 = 1048576
  const size_t OM_OFF   = 26214400;          // 4096*256*4 = 4194304
  const size_t Z1_OFF   = 30408704;          // 65536
  const size_t Z2_OFF   = 30474240;          // 65536
  const size_t RAD_OFF  = 30539776;          // 16384
  const size_t FLAG_OFF = 30556160;          // 256
  const size_t OBF_OFF  = 30556416;          // 2097152
  const size_t BBF_OFF  = 32653568;          // 16777216
  const size_t PMAX_OFF = 49430784;          // 16*4096*4 = 262144
  const size_t PIDX_OFF = 49692928;          // 262144   end ~50 MB

  unsigned short* hmb = (unsigned short*)(ws + HMB_OFF);
  unsigned short* Whi = (unsigned short*)(ws + WHI_OFF);
  unsigned short* Wlo = (unsigned short*)(ws + WLO_OFF);
  unsigned short* wob = (unsigned short*)(ws + WOB_OFF);
  float* om  = (float*)(ws + OM_OFF);
  float* z1  = (float*)(ws + Z1_OFF);
  float* z2  = (float*)(ws + Z2_OFF);
  float* rad = (float*)(ws + RAD_OFF);
  int*   flg = (int*)(ws + FLAG_OFF);
  unsigned short* obf = (unsigned short*)(ws + OBF_OFF);
  unsigned short* bbf = (unsigned short*)(ws + BBF_OFF);
  float* pmax = (float*)(ws + PMAX_OFF);
  int*   pidx = (int*)(ws + PIDX_OFF);

  float* out0 = (float*)d_out;            // [T,D] obs_beliefs
  float* out1 = out0 + (size_t)TT*DD;     // [T] sims_out
  float* out2 = out1 + TT;                // [T] slots
  float* out3 = out2 + TT;                // [T] meaningful

  hipMemsetAsync(ws + Z1_OFF, 0, 2*MM*sizeof(float), stream);

  k_mean    <<<TT*HH/4/256, 256, 0, stream>>>(hidden, hmb);
  k_cvt_w   <<<(1024*HH/4)/256, 256, 0, stream>>>(W_g1, W_p1, Whi, Wlo);
  k_cvt_wobs<<<(DD*HH/4)/256, 256, 0, stream>>>(W_obs, wob);
  k_obs     <<<dim3(DD/128, TT/128), 256, 0, stream>>>(hmb, wob, om);
  k_gp      <<<dim3(4, MM/128), 256, 0, stream>>>(hidden, Whi, Wlo, b_g1, b_p1,
                                                  W_g2, W_p2, z1, z2);
  k_obs_fin <<<TT, 256, 0, stream>>>(om, z1, z2, b_g2, b_p2, out0, out3, rad, obf);
  k_beliefs <<<NN/4, 256, 0, stream>>>(beliefs, bbf);
  k_any     <<<1, 256, 0, stream>>>(amask, flg);
  k_sims    <<<dim3(TT/128, 16), 256, 0, stream>>>(obf, bbf, amask, pmax, pidx);
  k_combine <<<TT/256, 256, 0, stream>>>(pmax, pidx, rad, flg, out1, out2);
}

// Round 4
// 645.372 us; speedup vs baseline: 1.3250x; 1.3250x over previous
//
#include <hip/hip_runtime.h>
#include <hip/hip_bf16.h>
#include <math.h>

#define TB 4
#define TT 4096
#define HH 2048
#define DD 256
#define NN 32768
#define HQ 512
#define MM (TB*TT)

typedef __attribute__((ext_vector_type(8))) short bf16x8;
typedef __attribute__((ext_vector_type(8))) _Float16 f16x8;
typedef __attribute__((ext_vector_type(4))) float f32x4;

__device__ inline unsigned short f2bf(float x){
  __hip_bfloat16 h = __float2bfloat16(x);
  return *reinterpret_cast<unsigned short*>(&h);
}

__device__ inline unsigned short f2h(float x){
  _Float16 h = (_Float16)x;
  unsigned short u; __builtin_memcpy(&u, &h, 2); return u;
}

__device__ inline bf16x8 as_bf16x8(uint4 u){ bf16x8 r; __builtin_memcpy(&r,&u,16); return r; }

// K1: batch-mean only (bf16 out)
__global__ __launch_bounds__(256) void k_mean(const float* __restrict__ h,
    unsigned short* __restrict__ hmb){
  const size_t i = (size_t)blockIdx.x*256 + threadIdx.x;   // float4 idx in [T*H/4]
  const size_t TH4 = (size_t)TT*HH/4;
  const float4* p = (const float4*)h;
  float4 v0 = p[i], v1 = p[i+TH4], v2 = p[i+2*TH4], v3 = p[i+3*TH4];
  float4 m;
  m.x = 0.25f*(v0.x+v1.x+v2.x+v3.x);
  m.y = 0.25f*(v0.y+v1.y+v2.y+v3.y);
  m.z = 0.25f*(v0.z+v1.z+v2.z+v3.z);
  m.w = 0.25f*(v0.w+v1.w+v2.w+v3.w);
  ushort4 o; o.x = f2bf(m.x); o.y = f2bf(m.y); o.z = f2bf(m.z); o.w = f2bf(m.w);
  *(ushort4*)(hmb + i*4) = o;
}

// K2: W_g1||W_p1 -> fp16 single [1024,2048]
__global__ __launch_bounds__(256) void k_cvt_w(const float* __restrict__ Wg1,
    const float* __restrict__ Wp1, unsigned short* __restrict__ Wh){
  const int idx4 = blockIdx.x*256 + threadIdx.x;     // 524288 float4s
  const int n = idx4 >> 9;                           // row 0..1023
  const int c = (idx4 & 511)*4;
  const float* src = (n < HQ) ? (Wg1 + (size_t)n*HH + c) : (Wp1 + (size_t)(n-HQ)*HH + c);
  float4 v = *(const float4*)src;
  ushort4 o; o.x = f2h(v.x); o.y = f2h(v.y); o.z = f2h(v.z); o.w = f2h(v.w);
  *(ushort4*)(Wh + (size_t)idx4*4) = o;
}

// K2b: W_obs -> bf16 [256,2048]
__global__ __launch_bounds__(256) void k_cvt_wobs(const float* __restrict__ W,
    unsigned short* __restrict__ Wb){
  const int idx4 = blockIdx.x*256 + threadIdx.x;     // 131072 float4s
  float4 v = *(const float4*)(W + (size_t)idx4*4);
  ushort4 o; o.x = f2bf(v.x); o.y = f2bf(v.y); o.z = f2bf(v.z); o.w = f2bf(v.w);
  *(ushort4*)(Wb + (size_t)idx4*4) = o;
}

// K3: obs_mean = hmb @ wob^T  (bf16 MFMA, f32 out)  [4096,2048]x[256,2048]^T
__global__ __launch_bounds__(256) void k_obs(const unsigned short* __restrict__ A,
    const unsigned short* __restrict__ Bw, float* __restrict__ C){
  const int n0 = blockIdx.x*128, m0 = blockIdx.y*128;
  const int tid = threadIdx.x;
  const int w = tid>>6, lane = tid&63, lr = lane&15, q = lane>>4;
  __shared__ __align__(16) unsigned short Bs[128][40];
  f32x4 acc[2][8] = {};
  for (int k0 = 0; k0 < HH; k0 += 32){
    __syncthreads();
    #pragma unroll
    for (int ii = 0; ii < 2; ii++){
      int idx = tid + ii*256;
      int row = idx >> 2, c8 = (idx & 3)*8;
      *(uint4*)&Bs[row][c8] = *(const uint4*)(Bw + (size_t)(n0+row)*HH + k0 + c8);
    }
    bf16x8 a[2];
    #pragma unroll
    for (int i = 0; i < 2; i++)
      a[i] = as_bf16x8(*(const uint4*)(A + (size_t)(m0 + w*32 + i*16 + lr)*HH + k0 + q*8));
    __syncthreads();
    #pragma unroll
    for (int j = 0; j < 8; j++){
      bf16x8 b = as_bf16x8(*(const uint4*)&Bs[j*16 + lr][q*8]);
      #pragma unroll
      for (int i = 0; i < 2; i++)
        acc[i][j] = __builtin_amdgcn_mfma_f32_16x16x32_bf16(a[i], b, acc[i][j], 0, 0, 0);
    }
  }
  #pragma unroll
  for (int i = 0; i < 2; i++)
    #pragma unroll
    for (int j = 0; j < 8; j++)
      #pragma unroll
      for (int r = 0; r < 4; r++)
        C[(size_t)(m0 + w*32 + i*16 + q*4 + r)*DD + n0 + j*16 + lr] = acc[i][j][r];
}

// K4: gate/prec layer1. fp16 2-product (A = ah+al split in-kernel, W fp16),
// XOR-swizzled 8KB LDS for W, small reg prefetch, fused relu*w2 epilogue.
// BM=128, BN=128, BK=32. grid (1024/128=8, 16384/128=128).
__global__ __launch_bounds__(256, 2) void k_gp(const float* __restrict__ A,
    const unsigned short* __restrict__ Wh,
    const float* __restrict__ bg1, const float* __restrict__ bp1,
    const float* __restrict__ Wg2, const float* __restrict__ Wp2,
    float* __restrict__ z1, float* __restrict__ z2){
  const int n0 = blockIdx.x*128;
  const int m0 = blockIdx.y*128;
  const int tid = threadIdx.x;
  const int w = tid>>6, lane = tid&63, lr = lane&15, q = lane>>4;
  // LDS: 128 rows x 32 halfs, chunk (8 halfs) at position (cpos ^ (row&3))
  __shared__ __align__(16) unsigned short Bs[128*32];
  f32x4 acc[2][8] = {};

  // staging map: thread covers chunks c = tid, tid+256
  const int sr0 = tid >> 2, sc0 = tid & 3;          // chunk 1: row sr0, col sc0
  const int sp0 = sc0 ^ (sr0 & 3);
  const int sr1 = 64 + sr0;                         // chunk 2
  const int sp1 = sc0 ^ (sr1 & 3);
  const unsigned short* wgp0 = Wh + (size_t)(n0 + sr0)*HH + sc0*8;
  const unsigned short* wgp1 = Wh + (size_t)(n0 + sr1)*HH + sc0*8;
  // A row pointers (2 m-tiles per wave)
  const float* arp0 = A + (size_t)(m0 + w*32 + lr)*HH + q*8;
  const float* arp1 = A + (size_t)(m0 + w*32 + 16 + lr)*HH + q*8;
  // read addr for B frags: row j*16+lr, chunk q^(lr&3)
  const int rp = (q ^ (lr & 3))*8 + lr*32;

  uint4 wreg0 = *(const uint4*)(wgp0);
  uint4 wreg1 = *(const uint4*)(wgp1);
  float4 a00 = *(const float4*)(arp0), a01 = *(const float4*)(arp0 + 4);
  float4 a10 = *(const float4*)(arp1), a11 = *(const float4*)(arp1 + 4);

  for (int k0 = 0; k0 < HH; k0 += 32){
    const bool last = (k0 + 32 >= HH);
    __syncthreads();
    *(uint4*)&Bs[sr0*32 + sp0*8] = wreg0;
    *(uint4*)&Bs[sr1*32 + sp1*8] = wreg1;
    __syncthreads();
    // split current A into fp16 hi/lo frags
    f16x8 ah[2], al[2];
    {
      float av0[8] = {a00.x,a00.y,a00.z,a00.w,a01.x,a01.y,a01.z,a01.w};
      float av1[8] = {a10.x,a10.y,a10.z,a10.w,a11.x,a11.y,a11.z,a11.w};
      #pragma unroll
      for (int e = 0; e < 8; e++){
        _Float16 h0 = (_Float16)av0[e];
        ah[0][e] = h0; al[0][e] = (_Float16)(av0[e] - (float)h0);
        _Float16 h1 = (_Float16)av1[e];
        ah[1][e] = h1; al[1][e] = (_Float16)(av1[e] - (float)h1);
      }
    }
    // prefetch next chunk (latency hidden under MFMA block)
    if (!last){
      wreg0 = *(const uint4*)(wgp0 + k0 + 32);
      wreg1 = *(const uint4*)(wgp1 + k0 + 32);
      a00 = *(const float4*)(arp0 + k0 + 32); a01 = *(const float4*)(arp0 + k0 + 36);
      a10 = *(const float4*)(arp1 + k0 + 32); a11 = *(const float4*)(arp1 + k0 + 36);
    }
    #pragma unroll
    for (int j = 0; j < 8; j++){
      f16x8 bh;
      __builtin_memcpy(&bh, &Bs[j*512 + rp], 16);
      #pragma unroll
      for (int i = 0; i < 2; i++){
        acc[i][j] = __builtin_amdgcn_mfma_f32_16x16x32_f16(ah[i], bh, acc[i][j], 0, 0, 0);
        acc[i][j] = __builtin_amdgcn_mfma_f32_16x16x32_f16(al[i], bh, acc[i][j], 0, 0, 0);
      }
    }
  }
  // epilogue: z[m] += sum_n relu(C[m,n] + b1[n]) * w2[n]
  const bool isP = (n0 >= HQ);
  const float* b1 = isP ? bp1 : bg1;
  const float* w2 = isP ? Wp2 : Wg2;
  float* zt = isP ? z2 : z1;
  const int nb = n0 - (isP ? HQ : 0);
  float bv[8], wv[8];
  #pragma unroll
  for (int j = 0; j < 8; j++){
    int n = nb + j*16 + lr;
    bv[j] = b1[n]; wv[j] = w2[n];
  }
  #pragma unroll
  for (int i = 0; i < 2; i++){
    float s[4];
    #pragma unroll
    for (int r = 0; r < 4; r++){
      float t = 0.f;
      #pragma unroll
      for (int j = 0; j < 8; j++)
        t += fmaxf(acc[i][j][r] + bv[j], 0.f) * wv[j];
      s[r] = t;
    }
    #pragma unroll
    for (int mk = 1; mk < 16; mk <<= 1)
      #pragma unroll
      for (int r = 0; r < 4; r++)
        s[r] += __shfl_xor(s[r], mk);
    if (lr == 0){
      #pragma unroll
      for (int r = 0; r < 4; r++)
        atomicAdd(&zt[m0 + w*32 + i*16 + q*4 + r], s[r]);
    }
  }
}

// K5: per-t finalize
__global__ __launch_bounds__(256) void k_obs_fin(const float* __restrict__ obs_mean,
    const float* __restrict__ z1, const float* __restrict__ z2,
    const float* __restrict__ bg2, const float* __restrict__ bp2,
    float* __restrict__ out0, float* __restrict__ out3,
    float* __restrict__ obs_radii, unsigned short* __restrict__ obf){
  const int t = blockIdx.x, tid = threadIdx.x;
  __shared__ float red[256];
  __shared__ float pmsh;
  if (tid < TB){
    float a = z1[tid*TT + t] + bg2[0];
    float b = z2[tid*TT + t] + bp2[0];
    float gate = 1.f/(1.f + expf(-a));
    float sp = (b > 0.f) ? (b + log1pf(expf(-b))) : log1pf(expf(b));
    red[tid] = gate * sp;
  }
  __syncthreads();
  if (tid == 0) pmsh = 0.25f*(red[0]+red[1]+red[2]+red[3]);
  __syncthreads();
  const float x = obs_mean[(size_t)t*DD + tid];
  red[tid] = x*x;
  __syncthreads();
  #pragma unroll
  for (int s = 128; s > 0; s >>= 1){ if (tid < s) red[tid] += red[tid+s]; __syncthreads(); }
  const float nrm = sqrtf(red[0]);
  const float pm = pmsh;
  __syncthreads();
  const float ob = (x / fmaxf(nrm, 1e-8f)) * pm;
  out0[(size_t)t*DD + tid] = ob;
  red[tid] = ob*ob;
  __syncthreads();
  #pragma unroll
  for (int s = 128; s > 0; s >>= 1){ if (tid < s) red[tid] += red[tid+s]; __syncthreads(); }
  const float r2 = sqrtf(red[0]);
  if (tid == 0){
    obs_radii[t] = r2;
    out3[t] = (r2 > 0.05f) ? 1.f : 0.f;
  }
  const float oa = ob / fmaxf(r2, 1e-8f);
  obf[(size_t)t*DD + tid] = f2bf(oa);
}

// K6: normalize beliefs -> bf16 angles
__global__ __launch_bounds__(256) void k_beliefs(const float* __restrict__ bel,
    unsigned short* __restrict__ bbf){
  const int n = (blockIdx.x*256 + threadIdx.x) >> 6;
  const int lane = threadIdx.x & 63;
  const float4 v = *(const float4*)(bel + (size_t)n*DD + lane*4);
  float s = v.x*v.x + v.y*v.y + v.z*v.z + v.w*v.w;
  #pragma unroll
  for (int m = 1; m < 64; m <<= 1) s += __shfl_xor(s, m);
  const float inv = 1.f / fmaxf(sqrtf(s), 1e-8f);
  ushort4 o;
  o.x = f2bf(v.x*inv); o.y = f2bf(v.y*inv); o.z = f2bf(v.z*inv); o.w = f2bf(v.w*inv);
  *(ushort4*)(bbf + (size_t)n*DD + lane*4) = o;
}

// K6b: any_active flag
__global__ __launch_bounds__(256) void k_any(const unsigned char* __restrict__ mask,
    int* __restrict__ flag){
  __shared__ int s;
  if (threadIdx.x == 0) s = 0;
  __syncthreads();
  int any = 0;
  for (int i = threadIdx.x; i < NN; i += 256) any |= (mask[i] != 0);
  if (any) s = 1;
  __syncthreads();
  if (threadIdx.x == 0) flag[0] = s;
}

// K7: fused sims + masked max/argmax. t_block=128 (2 m-tiles/wave), 32 n-splits,
// XOR-swizzled 32KB LDS B-tile (conflict-free).
__global__ __launch_bounds__(256) void k_sims(const unsigned short* __restrict__ obf,
    const unsigned short* __restrict__ bbf, const unsigned char* __restrict__ mask,
    float* __restrict__ pmax, int* __restrict__ pidx){
  const int t0 = blockIdx.x * 128;
  const int ns = blockIdx.y;                 // 0..31
  const int nbase0 = ns * (NN/32);
  const int tid = threadIdx.x;
  const int w = tid >> 6, lane = tid & 63;
  const int lr = lane & 15, q = lane >> 4;
  __shared__ __align__(16) unsigned short bt[64*256];
  __shared__ unsigned char am[64];
  bf16x8 afr[2][8];
  #pragma unroll
  for (int i = 0; i < 2; i++){
    const unsigned short* ap = obf + (size_t)(t0 + w*32 + i*16 + lr)*DD + q*8;
    #pragma unroll
    for (int ks = 0; ks < 8; ks++)
      afr[i][ks] = as_bf16x8(*(const uint4*)(ap + ks*32));
  }
  float vmax[2][4] = {{-INFINITY,-INFINITY,-INFINITY,-INFINITY},
                      {-INFINITY,-INFINITY,-INFINITY,-INFINITY}};
  int   vidx[2][4] = {{-1,-1,-1,-1},{-1,-1,-1,-1}};
  for (int it = 0; it < (NN/32)/64; it++){
    const int nb = nbase0 + it*64;
    __syncthreads();
    {
      const unsigned short* src = bbf + (size_t)nb*DD;
      #pragma unroll
      for (int i = 0; i < 8; i++){
        int c = tid + i*256;
        int row = c >> 5, c16 = c & 31;
        int p = c16 ^ (row & 31);
        uint4 u = *(const uint4*)(src + row*DD + c16*8);
        *(uint4*)(bt + row*256 + p*8) = u;
      }
      if (tid < 64) am[tid] = mask[nb + tid];
    }
    __syncthreads();
    #pragma unroll
    for (int sub = 0; sub < 4; sub++){
      f32x4 acc[2] = {{0.f,0.f,0.f,0.f},{0.f,0.f,0.f,0.f}};
      const int row = sub*16 + lr;
      const unsigned short* bp = bt + row*256;
      const int rx = row & 31;
      #pragma unroll
      for (int ks = 0; ks < 8; ks++){
        const int p = (q + ks*4) ^ rx;
        bf16x8 bfr = as_bf16x8(*(const uint4*)(bp + p*8));
        #pragma unroll
        for (int i = 0; i < 2; i++)
          acc[i] = __builtin_amdgcn_mfma_f32_16x16x32_bf16(afr[i][ks], bfr, acc[i], 0, 0, 0);
      }
      if (am[sub*16 + lr]){
        const int n = nb + sub*16 + lr;
        #pragma unroll
        for (int i = 0; i < 2; i++)
          #pragma unroll
          for (int r = 0; r < 4; r++)
            if (acc[i][r] > vmax[i][r]){ vmax[i][r] = acc[i][r]; vidx[i][r] = n; }
      }
    }
  }
  #pragma unroll
  for (int mk = 1; mk < 16; mk <<= 1){
    #pragma unroll
    for (int i = 0; i < 2; i++)
      #pragma unroll
      for (int r = 0; r < 4; r++){
        float om = __shfl_xor(vmax[i][r], mk);
        int   oi = __shfl_xor(vidx[i][r], mk);
        if (om > vmax[i][r] || (om == vmax[i][r] && (unsigned)oi < (unsigned)vidx[i][r])){
          vmax[i][r] = om; vidx[i][r] = oi;
        }
      }
  }
  if (lr == 0){
    #pragma unroll
    for (int i = 0; i < 2; i++)
      #pragma unroll
      for (int r = 0; r < 4; r++){
        const int t = t0 + w*32 + i*16 + q*4 + r;
        pmax[ns*TT + t] = vmax[i][r];
        pidx[ns*TT + t] = vidx[i][r];
      }
  }
}

// K8: combine n-splits + match logic
__global__ __launch_bounds__(256) void k_combine(const float* __restrict__ pmax,
    const int* __restrict__ pidx, const float* __restrict__ obs_radii,
    const int* __restrict__ flag, float* __restrict__ out1, float* __restrict__ out2){
  const int t = blockIdx.x*256 + threadIdx.x;
  float best = -INFINITY; int bi = -1;
  #pragma unroll
  for (int s = 0; s < 32; s++){
    float m = pmax[s*TT + t];
    if (m > best){ best = m; bi = pidx[s*TT + t]; }
  }
  const bool anyA = (flag[0] != 0);
  const bool mf = obs_radii[t] > 0.05f;
  const bool matched = mf && anyA && (best > 0.5f);
  out1[t] = matched ? best : 0.f;
  out2[t] = matched ? (float)bi : -1.f;
}

extern "C" void kernel_launch(void* const* d_in, const int* in_sizes, int n_in,
                              void* d_out, int out_size, void* d_ws, size_t ws_size,
                              hipStream_t stream) {
  const float* hidden = (const float*)d_in[0];
  const float* beliefs = (const float*)d_in[1];
  const unsigned char* amask = (const unsigned char*)d_in[2];
  const float* W_obs = (const float*)d_in[3];
  const float* W_g1 = (const float*)d_in[4];
  const float* b_g1 = (const float*)d_in[5];
  const float* W_g2 = (const float*)d_in[6];
  const float* b_g2 = (const float*)d_in[7];
  const float* W_p1 = (const float*)d_in[8];
  const float* b_p1 = (const float*)d_in[9];
  const float* W_p2 = (const float*)d_in[10];
  const float* b_p2 = (const float*)d_in[11];

  char* ws = (char*)d_ws;
  const size_t HMB_OFF  = 0;                 // 16777216
  const size_t WH_OFF   = 16777216;          // 1024*2048*2 = 4194304
  const size_t WOB_OFF  = 20971520;          // 1048576
  const size_t OM_OFF   = 22020096;          // 4194304
  const size_t Z1_OFF   = 26214400;          // 65536
  const size_t Z2_OFF   = 26279936;          // 65536
  const size_t RAD_OFF  = 26345472;          // 16384
  const size_t FLAG_OFF = 26361856;          // 256
  const size_t OBF_OFF  = 26362112;          // 2097152
  const size_t BBF_OFF  = 28459264;          // 16777216
  const size_t PMAX_OFF = 45236480;          // 32*4096*4 = 524288
  const size_t PIDX_OFF = 45760768;          // 524288    end ~46.3 MB

  unsigned short* hmb = (unsigned short*)(ws + HMB_OFF);
  unsigned short* Wh  = (unsigned short*)(ws + WH_OFF);
  unsigned short* wob = (unsigned short*)(ws + WOB_OFF);
  float* om  = (float*)(ws + OM_OFF);
  float* z1  = (float*)(ws + Z1_OFF);
  float* z2  = (float*)(ws + Z2_OFF);
  float* rad = (float*)(ws + RAD_OFF);
  int*   flg = (int*)(ws + FLAG_OFF);
  unsigned short* obf = (unsigned short*)(ws + OBF_OFF);
  unsigned short* bbf = (unsigned short*)(ws + BBF_OFF);
  float* pmax = (float*)(ws + PMAX_OFF);
  int*   pidx = (int*)(ws + PIDX_OFF);

  float* out0 = (float*)d_out;            // [T,D] obs_beliefs
  float* out1 = out0 + (size_t)TT*DD;     // [T] sims_out
  float* out2 = out1 + TT;                // [T] slots
  float* out3 = out2 + TT;                // [T] meaningful

  hipMemsetAsync(ws + Z1_OFF, 0, 2*MM*sizeof(float), stream);

  k_mean    <<<TT*HH/4/256, 256, 0, stream>>>(hidden, hmb);
  k_cvt_w   <<<(1024*HH/4)/256, 256, 0, stream>>>(W_g1, W_p1, Wh);
  k_cvt_wobs<<<(DD*HH/4)/256, 256, 0, stream>>>(W_obs, wob);
  k_obs     <<<dim3(DD/128, TT/128), 256, 0, stream>>>(hmb, wob, om);
  k_gp      <<<dim3(8, MM/128), 256, 0, stream>>>(hidden, Wh, b_g1, b_p1,
                                                  W_g2, W_p2, z1, z2);
  k_obs_fin <<<TT, 256, 0, stream>>>(om, z1, z2, b_g2, b_p2, out0, out3, rad, obf);
  k_beliefs <<<NN/4, 256, 0, stream>>>(beliefs, bbf);
  k_any     <<<1, 256, 0, stream>>>(amask, flg);
  k_sims    <<<dim3(TT/128, 32), 256, 0, stream>>>(obf, bbf, amask, pmax, pidx);
  k_combine <<<TT/256, 256, 0, stream>>>(pmax, pidx, rad, flg, out1, out2);
}

// Round 5
// 644.837 us; speedup vs baseline: 1.3261x; 1.0008x over previous
//
#include <hip/hip_runtime.h>
#include <hip/hip_bf16.h>
#include <math.h>

#define TB 4
#define TT 4096
#define HH 2048
#define DD 256
#define NN 32768
#define HQ 512
#define MM (TB*TT)

typedef __attribute__((ext_vector_type(8))) short bf16x8;
typedef __attribute__((ext_vector_type(8))) _Float16 f16x8;
typedef __attribute__((ext_vector_type(4))) float f32x4;

__device__ inline unsigned short f2bf(float x){
  __hip_bfloat16 h = __float2bfloat16(x);
  return *reinterpret_cast<unsigned short*>(&h);
}

__device__ inline unsigned short f2h(float x){
  _Float16 h = (_Float16)x;
  unsigned short u; __builtin_memcpy(&u, &h, 2); return u;
}

__device__ inline bf16x8 as_bf16x8(uint4 u){ bf16x8 r; __builtin_memcpy(&r,&u,16); return r; }

// K1: batch-mean only (bf16 out)
__global__ __launch_bounds__(256) void k_mean(const float* __restrict__ h,
    unsigned short* __restrict__ hmb){
  const size_t i = (size_t)blockIdx.x*256 + threadIdx.x;   // float4 idx in [T*H/4]
  const size_t TH4 = (size_t)TT*HH/4;
  const float4* p = (const float4*)h;
  float4 v0 = p[i], v1 = p[i+TH4], v2 = p[i+2*TH4], v3 = p[i+3*TH4];
  float4 m;
  m.x = 0.25f*(v0.x+v1.x+v2.x+v3.x);
  m.y = 0.25f*(v0.y+v1.y+v2.y+v3.y);
  m.z = 0.25f*(v0.z+v1.z+v2.z+v3.z);
  m.w = 0.25f*(v0.w+v1.w+v2.w+v3.w);
  ushort4 o; o.x = f2bf(m.x); o.y = f2bf(m.y); o.z = f2bf(m.z); o.w = f2bf(m.w);
  *(ushort4*)(hmb + i*4) = o;
}

// K2: W_g1||W_p1 -> fp16, pre-swizzled tile-linear layout for k_gp.
// Tiles: [nb 0..3][kc 0..63] of 256 rows x 32 halfs; within tile:
// addr = r*32 + ((c8 ^ s(r))<<3) + (k&7), s(r) = (r&3)^((r>>2)&3)
__global__ __launch_bounds__(256) void k_cvt_w(const float* __restrict__ Wg1,
    const float* __restrict__ Wp1, unsigned short* __restrict__ Wsw){
  const int id = blockIdx.x*256 + threadIdx.x;       // 262144 8-half chunks
  const int n = id >> 8;                             // row 0..1023
  const int cg = id & 255;                           // chunk in row
  const int k = cg*8;
  const int kc = cg >> 2;
  const int c8 = cg & 3;
  const float* src = (n < HQ) ? (Wg1 + (size_t)n*HH + k) : (Wp1 + (size_t)(n-HQ)*HH + k);
  float4 v0 = *(const float4*)src;
  float4 v1 = *(const float4*)(src + 4);
  unsigned short o[8] = {f2h(v0.x),f2h(v0.y),f2h(v0.z),f2h(v0.w),
                         f2h(v1.x),f2h(v1.y),f2h(v1.z),f2h(v1.w)};
  const int nb = n >> 8, r = n & 255;
  const int s = (r & 3) ^ ((r >> 2) & 3);
  unsigned short* dst = Wsw + ((size_t)(nb*64 + kc))*8192 + r*32 + ((c8 ^ s) << 3);
  __builtin_memcpy(dst, o, 16);
}

// K2b: W_obs -> bf16 [256,2048]
__global__ __launch_bounds__(256) void k_cvt_wobs(const float* __restrict__ W,
    unsigned short* __restrict__ Wb){
  const int idx4 = blockIdx.x*256 + threadIdx.x;     // 131072 float4s
  float4 v = *(const float4*)(W + (size_t)idx4*4);
  ushort4 o; o.x = f2bf(v.x); o.y = f2bf(v.y); o.z = f2bf(v.z); o.w = f2bf(v.w);
  *(ushort4*)(Wb + (size_t)idx4*4) = o;
}

// K3: obs_mean = hmb @ wob^T  (bf16 MFMA, f32 out)  [4096,2048]x[256,2048]^T
__global__ __launch_bounds__(256) void k_obs(const unsigned short* __restrict__ A,
    const unsigned short* __restrict__ Bw, float* __restrict__ C){
  const int n0 = blockIdx.x*128, m0 = blockIdx.y*128;
  const int tid = threadIdx.x;
  const int w = tid>>6, lane = tid&63, lr = lane&15, q = lane>>4;
  __shared__ __align__(16) unsigned short Bs[128][40];
  f32x4 acc[2][8] = {};
  for (int k0 = 0; k0 < HH; k0 += 32){
    __syncthreads();
    #pragma unroll
    for (int ii = 0; ii < 2; ii++){
      int idx = tid + ii*256;
      int row = idx >> 2, c8 = (idx & 3)*8;
      *(uint4*)&Bs[row][c8] = *(const uint4*)(Bw + (size_t)(n0+row)*HH + k0 + c8);
    }
    bf16x8 a[2];
    #pragma unroll
    for (int i = 0; i < 2; i++)
      a[i] = as_bf16x8(*(const uint4*)(A + (size_t)(m0 + w*32 + i*16 + lr)*HH + k0 + q*8));
    __syncthreads();
    #pragma unroll
    for (int j = 0; j < 8; j++){
      bf16x8 b = as_bf16x8(*(const uint4*)&Bs[j*16 + lr][q*8]);
      #pragma unroll
      for (int i = 0; i < 2; i++)
        acc[i][j] = __builtin_amdgcn_mfma_f32_16x16x32_bf16(a[i], b, acc[i][j], 0, 0, 0);
    }
  }
  #pragma unroll
  for (int i = 0; i < 2; i++)
    #pragma unroll
    for (int j = 0; j < 8; j++)
      #pragma unroll
      for (int r = 0; r < 4; r++)
        C[(size_t)(m0 + w*32 + i*16 + q*4 + r)*DD + n0 + j*16 + lr] = acc[i][j][r];
}

// K4: gate/prec layer1. fp16 2-product, BM=128 BN=256 BK=32, pre-swizzled W
// (linear stage, conflict-free reads), reg prefetch, register-light epilogue.
// grid (4, 128).
__global__ __launch_bounds__(256, 2) void k_gp(const float* __restrict__ A,
    const unsigned short* __restrict__ Wsw,
    const float* __restrict__ bg1, const float* __restrict__ bp1,
    const float* __restrict__ Wg2, const float* __restrict__ Wp2,
    float* __restrict__ z1, float* __restrict__ z2){
  const int nb = blockIdx.x;          // 0..3 (n0 = nb*256)
  const int m0 = blockIdx.y*128;
  const int tid = threadIdx.x;
  const int w = tid>>6, lane = tid&63, lr = lane&15, q = lane>>4;
  __shared__ __align__(16) unsigned short Bs[8192];   // 16 KB tile
  f32x4 acc[2][16] = {};

  const unsigned short* wt = Wsw + (size_t)nb*64*8192;
  const int soff = w*2048 + lane*8;                   // staging offset (halfs), +i*512
  const float* arp0 = A + (size_t)(m0 + w*32 + lr)*HH + q*8;
  const float* arp1 = A + (size_t)(m0 + w*32 + 16 + lr)*HH + q*8;
  const int rpB = lr*32 + ((q ^ ((lr & 3) ^ ((lr >> 2) & 3))) << 3);  // + j*512

  uint4 wpf[4];
  #pragma unroll
  for (int i = 0; i < 4; i++) wpf[i] = *(const uint4*)(wt + soff + i*512);
  float4 a0[2], a1[2];
  a0[0] = *(const float4*)(arp0); a1[0] = *(const float4*)(arp0 + 4);
  a0[1] = *(const float4*)(arp1); a1[1] = *(const float4*)(arp1 + 4);

  for (int kc = 0; kc < 64; kc++){
    __syncthreads();
    #pragma unroll
    for (int i = 0; i < 4; i++) *(uint4*)(Bs + soff + i*512) = wpf[i];
    __syncthreads();
    // split current A fp32 -> fp16 hi/lo
    f16x8 ah[2], al[2];
    #pragma unroll
    for (int i = 0; i < 2; i++){
      float av[8] = {a0[i].x,a0[i].y,a0[i].z,a0[i].w,a1[i].x,a1[i].y,a1[i].z,a1[i].w};
      #pragma unroll
      for (int e = 0; e < 8; e++){
        _Float16 h = (_Float16)av[e];
        ah[i][e] = h; al[i][e] = (_Float16)(av[e] - (float)h);
      }
    }
    // prefetch next chunk (W + A) — latency hidden under MFMA block
    if (kc < 63){
      const unsigned short* wtn = wt + (size_t)(kc+1)*8192;
      #pragma unroll
      for (int i = 0; i < 4; i++) wpf[i] = *(const uint4*)(wtn + soff + i*512);
      const int ko = (kc+1)*32;
      a0[0] = *(const float4*)(arp0 + ko); a1[0] = *(const float4*)(arp0 + ko + 4);
      a0[1] = *(const float4*)(arp1 + ko); a1[1] = *(const float4*)(arp1 + ko + 4);
    }
    #pragma unroll
    for (int j = 0; j < 16; j++){
      f16x8 bh;
      __builtin_memcpy(&bh, Bs + j*512 + rpB, 16);
      acc[0][j] = __builtin_amdgcn_mfma_f32_16x16x32_f16(ah[0], bh, acc[0][j], 0, 0, 0);
      acc[1][j] = __builtin_amdgcn_mfma_f32_16x16x32_f16(ah[1], bh, acc[1][j], 0, 0, 0);
      acc[0][j] = __builtin_amdgcn_mfma_f32_16x16x32_f16(al[0], bh, acc[0][j], 0, 0, 0);
      acc[1][j] = __builtin_amdgcn_mfma_f32_16x16x32_f16(al[1], bh, acc[1][j], 0, 0, 0);
    }
  }
  // epilogue: z[m] += sum_n relu(C[m,n] + b1[n]) * w2[n]   (register-light)
  const bool isP = (nb >= 2);
  const float* b1 = isP ? bp1 : bg1;
  const float* w2 = isP ? Wp2 : Wg2;
  float* zt = isP ? z2 : z1;
  const int nbl = nb*256 - (isP ? HQ : 0);
  float s[2][4] = {};
  #pragma unroll
  for (int j = 0; j < 16; j++){
    const int n = nbl + j*16 + lr;
    const float bb = b1[n], ww = w2[n];
    #pragma unroll
    for (int i = 0; i < 2; i++)
      #pragma unroll
      for (int r = 0; r < 4; r++)
        s[i][r] += fmaxf(acc[i][j][r] + bb, 0.f) * ww;
  }
  #pragma unroll
  for (int mk = 1; mk < 16; mk <<= 1)
    #pragma unroll
    for (int i = 0; i < 2; i++)
      #pragma unroll
      for (int r = 0; r < 4; r++)
        s[i][r] += __shfl_xor(s[i][r], mk);
  if (lr == 0){
    #pragma unroll
    for (int i = 0; i < 2; i++)
      #pragma unroll
      for (int r = 0; r < 4; r++)
        atomicAdd(&zt[m0 + w*32 + i*16 + q*4 + r], s[i][r]);
  }
}

// K5: per-t finalize — one wave per t, shuffle reductions (no barriers)
__global__ __launch_bounds__(256) void k_obs_fin(const float* __restrict__ obs_mean,
    const float* __restrict__ z1, const float* __restrict__ z2,
    const float* __restrict__ bg2, const float* __restrict__ bp2,
    float* __restrict__ out0, float* __restrict__ out3,
    float* __restrict__ obs_radii, unsigned short* __restrict__ obf){
  const int w = threadIdx.x >> 6, lane = threadIdx.x & 63;
  const int t = blockIdx.x*4 + w;
  float pm = 0.f;
  if (lane < TB){
    float a = z1[lane*TT + t] + bg2[0];
    float b = z2[lane*TT + t] + bp2[0];
    float gate = 1.f/(1.f + expf(-a));
    float sp = (b > 0.f) ? (b + log1pf(expf(-b))) : log1pf(expf(b));
    pm = gate * sp;
  }
  #pragma unroll
  for (int m = 1; m < 4; m <<= 1) pm += __shfl_xor(pm, m);
  pm = __shfl(pm, 0) * 0.25f;
  float4 x = *(const float4*)(obs_mean + (size_t)t*DD + lane*4);
  float ss = x.x*x.x + x.y*x.y + x.z*x.z + x.w*x.w;
  #pragma unroll
  for (int m = 1; m < 64; m <<= 1) ss += __shfl_xor(ss, m);
  const float nrm = sqrtf(ss);
  const float sc = pm / fmaxf(nrm, 1e-8f);
  float4 ob = {x.x*sc, x.y*sc, x.z*sc, x.w*sc};
  *(float4*)(out0 + (size_t)t*DD + lane*4) = ob;
  float s2 = ob.x*ob.x + ob.y*ob.y + ob.z*ob.z + ob.w*ob.w;
  #pragma unroll
  for (int m = 1; m < 64; m <<= 1) s2 += __shfl_xor(s2, m);
  const float r2 = sqrtf(s2);
  if (lane == 0){
    obs_radii[t] = r2;
    out3[t] = (r2 > 0.05f) ? 1.f : 0.f;
  }
  const float inv2 = 1.f / fmaxf(r2, 1e-8f);
  ushort4 o = {f2bf(ob.x*inv2), f2bf(ob.y*inv2), f2bf(ob.z*inv2), f2bf(ob.w*inv2)};
  *(ushort4*)(obf + (size_t)t*DD + lane*4) = o;
}

// K6: normalize beliefs -> bf16 angles
__global__ __launch_bounds__(256) void k_beliefs(const float* __restrict__ bel,
    unsigned short* __restrict__ bbf){
  const int n = (blockIdx.x*256 + threadIdx.x) >> 6;
  const int lane = threadIdx.x & 63;
  const float4 v = *(const float4*)(bel + (size_t)n*DD + lane*4);
  float s = v.x*v.x + v.y*v.y + v.z*v.z + v.w*v.w;
  #pragma unroll
  for (int m = 1; m < 64; m <<= 1) s += __shfl_xor(s, m);
  const float inv = 1.f / fmaxf(sqrtf(s), 1e-8f);
  ushort4 o;
  o.x = f2bf(v.x*inv); o.y = f2bf(v.y*inv); o.z = f2bf(v.z*inv); o.w = f2bf(v.w*inv);
  *(ushort4*)(bbf + (size_t)n*DD + lane*4) = o;
}

// K6b: any_active flag — parallel, ballot + one atomic per wave
__global__ __launch_bounds__(256) void k_any(const unsigned char* __restrict__ mask,
    int* __restrict__ flag){
  const int i = blockIdx.x*256 + threadIdx.x;
  const int any = (mask[i] != 0) ? 1 : 0;
  if (__ballot(any)){
    if ((threadIdx.x & 63) == 0) atomicOr(flag, 1);
  }
}

// K7: fused sims + masked max/argmax. t_block=128 (2 m-tiles/wave), 32 n-splits,
// XOR-swizzled LDS B-tile (conflict-free).
__global__ __launch_bounds__(256) void k_sims(const unsigned short* __restrict__ obf,
    const unsigned short* __restrict__ bbf, const unsigned char* __restrict__ mask,
    float* __restrict__ pmax, int* __restrict__ pidx){
  const int t0 = blockIdx.x * 128;
  const int ns = blockIdx.y;                 // 0..31
  const int nbase0 = ns * (NN/32);
  const int tid = threadIdx.x;
  const int w = tid >> 6, lane = tid & 63;
  const int lr = lane & 15, q = lane >> 4;
  __shared__ __align__(16) unsigned short bt[64*256];
  __shared__ unsigned char am[64];
  bf16x8 afr[2][8];
  #pragma unroll
  for (int i = 0; i < 2; i++){
    const unsigned short* ap = obf + (size_t)(t0 + w*32 + i*16 + lr)*DD + q*8;
    #pragma unroll
    for (int ks = 0; ks < 8; ks++)
      afr[i][ks] = as_bf16x8(*(const uint4*)(ap + ks*32));
  }
  float vmax[2][4] = {{-INFINITY,-INFINITY,-INFINITY,-INFINITY},
                      {-INFINITY,-INFINITY,-INFINITY,-INFINITY}};
  int   vidx[2][4] = {{-1,-1,-1,-1},{-1,-1,-1,-1}};
  for (int it = 0; it < (NN/32)/64; it++){
    const int nb = nbase0 + it*64;
    __syncthreads();
    {
      const unsigned short* src = bbf + (size_t)nb*DD;
      #pragma unroll
      for (int i = 0; i < 8; i++){
        int c = tid + i*256;
        int row = c >> 5, c16 = c & 31;
        int p = c16 ^ (row & 31);
        uint4 u = *(const uint4*)(src + row*DD + c16*8);
        *(uint4*)(bt + row*256 + p*8) = u;
      }
      if (tid < 64) am[tid] = mask[nb + tid];
    }
    __syncthreads();
    #pragma unroll
    for (int sub = 0; sub < 4; sub++){
      f32x4 acc[2] = {{0.f,0.f,0.f,0.f},{0.f,0.f,0.f,0.f}};
      const int row = sub*16 + lr;
      const unsigned short* bp = bt + row*256;
      const int rx = row & 31;
      #pragma unroll
      for (int ks = 0; ks < 8; ks++){
        const int p = (q + ks*4) ^ rx;
        bf16x8 bfr = as_bf16x8(*(const uint4*)(bp + p*8));
        #pragma unroll
        for (int i = 0; i < 2; i++)
          acc[i] = __builtin_amdgcn_mfma_f32_16x16x32_bf16(afr[i][ks], bfr, acc[i], 0, 0, 0);
      }
      if (am[sub*16 + lr]){
        const int n = nb + sub*16 + lr;
        #pragma unroll
        for (int i = 0; i < 2; i++)
          #pragma unroll
          for (int r = 0; r < 4; r++)
            if (acc[i][r] > vmax[i][r]){ vmax[i][r] = acc[i][r]; vidx[i][r] = n; }
      }
    }
  }
  #pragma unroll
  for (int mk = 1; mk < 16; mk <<= 1){
    #pragma unroll
    for (int i = 0; i < 2; i++)
      #pragma unroll
      for (int r = 0; r < 4; r++){
        float om = __shfl_xor(vmax[i][r], mk);
        int   oi = __shfl_xor(vidx[i][r], mk);
        if (om > vmax[i][r] || (om == vmax[i][r] && (unsigned)oi < (unsigned)vidx[i][r])){
          vmax[i][r] = om; vidx[i][r] = oi;
        }
      }
  }
  if (lr == 0){
    #pragma unroll
    for (int i = 0; i < 2; i++)
      #pragma unroll
      for (int r = 0; r < 4; r++){
        const int t = t0 + w*32 + i*16 + q*4 + r;
        pmax[ns*TT + t] = vmax[i][r];
        pidx[ns*TT + t] = vidx[i][r];
      }
  }
}

// K8: combine n-splits + match logic
__global__ __launch_bounds__(256) void k_combine(const float* __restrict__ pmax,
    const int* __restrict__ pidx, const float* __restrict__ obs_radii,
    const int* __restrict__ flag, float* __restrict__ out1, float* __restrict__ out2){
  const int t = blockIdx.x*256 + threadIdx.x;
  float best = -INFINITY; int bi = -1;
  #pragma unroll
  for (int s = 0; s < 32; s++){
    float m = pmax[s*TT + t];
    if (m > best){ best = m; bi = pidx[s*TT + t]; }
  }
  const bool anyA = (flag[0] != 0);
  const bool mf = obs_radii[t] > 0.05f;
  const bool matched = mf && anyA && (best > 0.5f);
  out1[t] = matched ? best : 0.f;
  out2[t] = matched ? (float)bi : -1.f;
}

extern "C" void kernel_launch(void* const* d_in, const int* in_sizes, int n_in,
                              void* d_out, int out_size, void* d_ws, size_t ws_size,
                              hipStream_t stream) {
  const float* hidden = (const float*)d_in[0];
  const float* beliefs = (const float*)d_in[1];
  const unsigned char* amask = (const unsigned char*)d_in[2];
  const float* W_obs = (const float*)d_in[3];
  const float* W_g1 = (const float*)d_in[4];
  const float* b_g1 = (const float*)d_in[5];
  const float* W_g2 = (const float*)d_in[6];
  const float* b_g2 = (const float*)d_in[7];
  const float* W_p1 = (const float*)d_in[8];
  const float* b_p1 = (const float*)d_in[9];
  const float* W_p2 = (const float*)d_in[10];
  const float* b_p2 = (const float*)d_in[11];

  char* ws = (char*)d_ws;
  const size_t HMB_OFF  = 0;                 // 16777216
  const size_t WSW_OFF  = 16777216;          // 1024*2048*2 = 4194304 (swizzled)
  const size_t WOB_OFF  = 20971520;          // 1048576
  const size_t OM_OFF   = 22020096;          // 4194304
  const size_t Z1_OFF   = 26214400;          // 65536
  const size_t Z2_OFF   = 26279936;          // 65536
  const size_t FLAG_OFF = 26345472;          // 256  (contiguous with z1/z2 for memset)
  const size_t RAD_OFF  = 26345728;          // 16384
  const size_t OBF_OFF  = 26362112;          // 2097152
  const size_t BBF_OFF  = 28459264;          // 16777216
  const size_t PMAX_OFF = 45236480;          // 524288
  const size_t PIDX_OFF = 45760768;          // 524288    end ~46.3 MB

  unsigned short* hmb = (unsigned short*)(ws + HMB_OFF);
  unsigned short* Wsw = (unsigned short*)(ws + WSW_OFF);
  unsigned short* wob = (unsigned short*)(ws + WOB_OFF);
  float* om  = (float*)(ws + OM_OFF);
  float* z1  = (float*)(ws + Z1_OFF);
  float* z2  = (float*)(ws + Z2_OFF);
  int*   flg = (int*)(ws + FLAG_OFF);
  float* rad = (float*)(ws + RAD_OFF);
  unsigned short* obf = (unsigned short*)(ws + OBF_OFF);
  unsigned short* bbf = (unsigned short*)(ws + BBF_OFF);
  float* pmax = (float*)(ws + PMAX_OFF);
  int*   pidx = (int*)(ws + PIDX_OFF);

  float* out0 = (float*)d_out;            // [T,D] obs_beliefs
  float* out1 = out0 + (size_t)TT*DD;     // [T] sims_out
  float* out2 = out1 + TT;                // [T] slots
  float* out3 = out2 + TT;                // [T] meaningful

  hipMemsetAsync(ws + Z1_OFF, 0, 2*MM*sizeof(float) + 256, stream);  // z1,z2,flag

  k_mean    <<<TT*HH/4/256, 256, 0, stream>>>(hidden, hmb);
  k_cvt_w   <<<(1024*HH/8)/256, 256, 0, stream>>>(W_g1, W_p1, Wsw);
  k_cvt_wobs<<<(DD*HH/4)/256, 256, 0, stream>>>(W_obs, wob);
  k_obs     <<<dim3(DD/128, TT/128), 256, 0, stream>>>(hmb, wob, om);
  k_gp      <<<dim3(4, MM/128), 256, 0, stream>>>(hidden, Wsw, b_g1, b_p1,
                                                  W_g2, W_p2, z1, z2);
  k_obs_fin <<<TT/4, 256, 0, stream>>>(om, z1, z2, b_g2, b_p2, out0, out3, rad, obf);
  k_beliefs <<<NN/4, 256, 0, stream>>>(beliefs, bbf);
  k_any     <<<NN/256, 256, 0, stream>>>(amask, flg);
  k_sims    <<<dim3(TT/128, 32), 256, 0, stream>>>(obf, bbf, amask, pmax, pidx);
  k_combine <<<TT/256, 256, 0, stream>>>(pmax, pidx, rad, flg, out1, out2);
}